// Round 3
// baseline (215.513 us; speedup 1.0000x reference)
//
#include <hip/hip_runtime.h>

#define N_VERTS 53215
#define N_ROWS  (3 * N_VERTS)        // 159645
#define EXP_DIM 29
#define SHP_DIM 199
#define TOT_S   (N_ROWS * SHP_DIM)   // 31,769,355 floats (fits int32)
#define TOT_E   (N_ROWS * EXP_DIM)   // 4,629,705
#define STRIPS  ((N_ROWS + 15) / 16) // 9978
#define HEIGHT_F 450.0f
#define ASPECT_XY (224.0f / 450.0f)

// ---------------- Kernel 1: y[r] = u[r] + W_shp[r,:]@a_shp + W_exp[r,:]@a_exp
// Wave owns a 16-row strip. Lane = r16*4 + q: 4 lanes per row load 16-B-ALIGNED
// float4s on the global 16-B grid; the row-start misalignment (rows are 199
// floats = 796 B, not 16-B periodic) is absorbed by per-lane alpha registers
// read from a zero-padded LDS copy at offset (4 - shift). shift is strip-
// invariant: shiftS=(3*r16)&3, shiftE=r16&3. Out-of-row grid elements get
// alpha=0. Per strip: 13 aligned float4 (shp) + 2 (exp) + 52+8 FMA + 2 shfl.
__global__ __launch_bounds__(256) void pca_gemv_kernel(
    const float* __restrict__ alpha_exp,  // 29
    const float* __restrict__ alpha_shp,  // 199
    const float* __restrict__ u_base,     // N_ROWS
    const float* __restrict__ w_exp,      // N_ROWS x 29
    const float* __restrict__ w_shp,      // N_ROWS x 199
    float* __restrict__ y)                // N_ROWS (workspace)
{
    __shared__ float als[212];  // als[4+c] = alpha_shp[c], zero-padded edges
    __shared__ float ale[40];   // ale[4+c] = alpha_exp[c], zero-padded edges

    const int t = threadIdx.x;
    if (t < 212) als[t] = (t >= 4 && t < 4 + SHP_DIM) ? alpha_shp[t - 4] : 0.0f;
    if (t >= 212 && t < 252) {
        const int u = t - 212;
        ale[u] = (u >= 4 && u < 4 + EXP_DIM) ? alpha_exp[u - 4] : 0.0f;
    }
    __syncthreads();

    const int lane = t & 63;
    const int q    = lane & 3;   // position within row's 4-lane group
    const int r16  = lane >> 2;  // row within strip
    const int wid  = (int)((blockIdx.x * blockDim.x + t) >> 6);
    const int nw   = (int)((gridDim.x * blockDim.x) >> 6);

    // shift = (row*dim) & 3 is the same for every strip (16*dim % 4 == 0).
    const int shiftS = (3 * r16) & 3;   // 199 % 4 == 3
    const int shiftE = r16 & 3;         // 29  % 4 == 1

    // Per-lane alpha fragments (loop-invariant) -> registers.
    float aS[13][4], aE[2][4];
    #pragma unroll
    for (int j = 0; j < 13; ++j)
        #pragma unroll
        for (int k = 0; k < 4; ++k)
            aS[j][k] = als[4 - shiftS + 4 * q + 16 * j + k];
    #pragma unroll
    for (int je = 0; je < 2; ++je)
        #pragma unroll
        for (int k = 0; k < 4; ++k)
            aE[je][k] = ale[4 - shiftE + 4 * q + 16 * je + k];

    for (int s = wid; s < STRIPS; s += nw) {
        const int rowv = s * 16 + r16;
        const int rowc = (rowv < N_ROWS) ? rowv : (N_ROWS - 1);
        const int b   = rowc * SHP_DIM;
        const int f0  = b - (b & 3);      // 16-B aligned grid start covering row
        const int be  = rowc * EXP_DIM;
        const int f0e = be - (be & 3);

        float sum = 0.0f;
        if (s != STRIPS - 1) {
            #pragma unroll
            for (int j = 0; j < 13; ++j) {
                const float4 w = *(const float4*)(w_shp + f0 + 4 * q + 16 * j);
                sum += w.x * aS[j][0] + w.y * aS[j][1] + w.z * aS[j][2] + w.w * aS[j][3];
            }
            #pragma unroll
            for (int je = 0; je < 2; ++je) {
                const float4 e = *(const float4*)(w_exp + f0e + 4 * q + 16 * je);
                sum += e.x * aE[je][0] + e.y * aE[je][1] + e.z * aE[je][2] + e.w * aE[je][3];
            }
        } else {
            // Last strip: clamped scalar loads so we never read past the
            // matrices (alpha=0 kills clamped/out-of-row terms).
            #pragma unroll
            for (int j = 0; j < 13; ++j) {
                const int base = f0 + 4 * q + 16 * j;
                #pragma unroll
                for (int k = 0; k < 4; ++k) {
                    const int idx = base + k;
                    sum += w_shp[idx < TOT_S ? idx : (TOT_S - 1)] * aS[j][k];
                }
            }
            #pragma unroll
            for (int je = 0; je < 2; ++je) {
                const int base = f0e + 4 * q + 16 * je;
                #pragma unroll
                for (int k = 0; k < 4; ++k) {
                    const int idx = base + k;
                    sum += w_exp[idx < TOT_E ? idx : (TOT_E - 1)] * aE[je][k];
                }
            }
        }

        // Reduce across the 4 lanes of each row (quad-local butterfly).
        sum += __shfl_xor(sum, 1, 64);
        sum += __shfl_xor(sum, 2, 64);

        if (q == 0 && rowv < N_ROWS)
            y[rowv] = sum + u_base[rowv];  // 16 lanes -> one 64-B segment
    }
}

// ---------------- Kernel 2: pose transform, one thread per vertex (~2 MB IO)
__global__ __launch_bounds__(256) void pca_pose_kernel(
    const float* __restrict__ pose,
    const float* __restrict__ y,
    float* __restrict__ out)
{
    const int v = blockIdx.x * blockDim.x + threadIdx.x;
    if (v >= N_VERTS) return;

    const float vx = y[3 * v + 0];
    const float vy = y[3 * v + 1];
    const float vz = y[3 * v + 2];

    const float p0 = pose[0], p1 = pose[1], p2  = pose[2],  p3  = pose[3];
    const float p4 = pose[4], p5 = pose[5], p6  = pose[6],  p7  = pose[7];
    const float p8 = pose[8], p9 = pose[9], p10 = pose[10], p11 = pose[11];
    const float s  = p3 + p7 + p11;

    float* o = out + (size_t)v * 3;
    o[0] = ASPECT_XY * (s * (p0 * vx + p1 * vy + p2  * vz) + p3);
    o[1] = ASPECT_XY * (HEIGHT_F - (s * (p4 * vx + p5 * vy + p6 * vz) + p7));
    o[2] = s * (p8 * vx + p9 * vy + p10 * vz);
}

extern "C" void kernel_launch(void* const* d_in, const int* in_sizes, int n_in,
                              void* d_out, int out_size, void* d_ws, size_t ws_size,
                              hipStream_t stream) {
    const float* pose      = (const float*)d_in[0];
    const float* alpha_exp = (const float*)d_in[1];
    const float* alpha_shp = (const float*)d_in[2];
    const float* u_base    = (const float*)d_in[3];
    const float* w_exp     = (const float*)d_in[4];
    const float* w_shp     = (const float*)d_in[5];
    float* out = (float*)d_out;
    float* y   = (float*)d_ws;   // N_ROWS floats << ws_size

    // 1248 blocks x 4 waves = 4992 waves, ~2 strips each (amortizes alpha init).
    pca_gemv_kernel<<<1248, 256, 0, stream>>>(
        alpha_exp, alpha_shp, u_base, w_exp, w_shp, y);

    pca_pose_kernel<<<(N_VERTS + 255) / 256, 256, 0, stream>>>(pose, y, out);
}

// Round 4
// 205.451 us; speedup vs baseline: 1.0490x; 1.0490x over previous
//
#include <hip/hip_runtime.h>

#define N_VERTS 53215
#define EXP_DIM 29
#define SHP_DIM 199
#define HEIGHT_F 450.0f
#define ASPECT_XY (224.0f / 450.0f)

// Grid-stride, wave-per-vertex, no barriers (R2 structure — best measured).
// Each 64-lane wave processes one vertex per iteration: 3 contiguous 199-float
// rows of w_shp (lane-strided, coalesced) + 3 rows of w_exp + u_base triple.
// Alpha slices are loop-invariant per lane -> 5 registers. 18 loads issued
// back-to-back per iteration (max MLP); u_base loads hoisted so their latency
// hides under the 18-shuffle reduction. 2048 blocks x 4 waves = 32 waves/CU.
__global__ __launch_bounds__(256, 8) void pca_transform_kernel(
    const float* __restrict__ pose,       // 12
    const float* __restrict__ alpha_exp,  // 29
    const float* __restrict__ alpha_shp,  // 199
    const float* __restrict__ u_base,     // 3*N_VERTS
    const float* __restrict__ w_exp,      // 3*N_VERTS x 29
    const float* __restrict__ w_shp,      // 3*N_VERTS x 199
    float* __restrict__ out)              // N_VERTS x 3
{
    const int lane   = threadIdx.x & 63;
    const int gwave  = (int)((blockIdx.x * blockDim.x + threadIdx.x) >> 6);
    const int nwaves = (int)((gridDim.x * blockDim.x) >> 6);

    // Pose is wave-uniform and loop-invariant -> SGPRs.
    const float p0 = pose[0], p1 = pose[1], p2  = pose[2],  p3  = pose[3];
    const float p4 = pose[4], p5 = pose[5], p6  = pose[6],  p7  = pose[7];
    const float p8 = pose[8], p9 = pose[9], p10 = pose[10], p11 = pose[11];
    const float s  = p3 + p7 + p11;

    // Per-lane alpha slice is loop-invariant: hoist to registers.
    // 199 = 3*64 + 7 ; clamp tail address, zero the weight (no exec-mask br).
    const int  k3 = (lane < 7)  ? lane + 192 : 198;
    const int  ke = (lane < EXP_DIM) ? lane : (EXP_DIM - 1);
    const float a0 = alpha_shp[lane];
    const float a1 = alpha_shp[lane + 64];
    const float a2 = alpha_shp[lane + 128];
    const float a3 = (lane < 7) ? alpha_shp[k3] : 0.0f;
    const float ae = (lane < EXP_DIM) ? alpha_exp[ke] : 0.0f;

    for (int v = gwave; v < N_VERTS; v += nwaves) {
        const float* __restrict__ sx_p = w_shp + (size_t)(3 * v) * SHP_DIM;
        const float* __restrict__ sy_p = sx_p + SHP_DIM;
        const float* __restrict__ sz_p = sy_p + SHP_DIM;
        const float* __restrict__ ex_p = w_exp + (size_t)(3 * v) * EXP_DIM;

        // Issue all loads back-to-back (max MLP), then reduce.
        const float x0 = sx_p[lane], x1 = sx_p[lane + 64], x2 = sx_p[lane + 128], x3 = sx_p[k3];
        const float y0 = sy_p[lane], y1 = sy_p[lane + 64], y2 = sy_p[lane + 128], y3 = sy_p[k3];
        const float z0 = sz_p[lane], z1 = sz_p[lane + 64], z2 = sz_p[lane + 128], z3 = sz_p[k3];
        const float xe = ex_p[ke], ye = ex_p[EXP_DIM + ke], ze = ex_p[2 * EXP_DIM + ke];
        // u_base loads issued BEFORE the shuffle chain so their latency is
        // hidden under the 18-shuffle reduction (R2 had them after).
        const float ux = u_base[3 * v + 0];
        const float uy = u_base[3 * v + 1];
        const float uz = u_base[3 * v + 2];

        float sx = x0 * a0 + x1 * a1 + x2 * a2 + x3 * a3 + xe * ae;
        float sy = y0 * a0 + y1 * a1 + y2 * a2 + y3 * a3 + ye * ae;
        float sz = z0 * a0 + z1 * a1 + z2 * a2 + z3 * a3 + ze * ae;

        // Three interleaved 64-lane butterflies (independent dep chains).
        #pragma unroll
        for (int off = 32; off > 0; off >>= 1) {
            sx += __shfl_xor(sx, off, 64);
            sy += __shfl_xor(sy, off, 64);
            sz += __shfl_xor(sz, off, 64);
        }

        const float vx = sx + ux;
        const float vy = sy + uy;
        const float vz = sz + uz;

        const float ox = ASPECT_XY * (s * (p0 * vx + p1 * vy + p2  * vz) + p3);
        const float oy = ASPECT_XY * (HEIGHT_F - (s * (p4 * vx + p5 * vy + p6 * vz) + p7));
        const float oz = s * (p8 * vx + p9 * vy + p10 * vz);

        if (lane == 0) {
            float* o = out + (size_t)v * 3;
            o[0] = ox; o[1] = oy; o[2] = oz;
        }
    }
}

extern "C" void kernel_launch(void* const* d_in, const int* in_sizes, int n_in,
                              void* d_out, int out_size, void* d_ws, size_t ws_size,
                              hipStream_t stream) {
    const float* pose      = (const float*)d_in[0];
    const float* alpha_exp = (const float*)d_in[1];
    const float* alpha_shp = (const float*)d_in[2];
    const float* u_base    = (const float*)d_in[3];
    const float* w_exp     = (const float*)d_in[4];
    const float* w_shp     = (const float*)d_in[5];
    float* out = (float*)d_out;

    // 2048 blocks x 256 thr = 8192 waves (32 waves/CU), ~6.5 vertices/wave.
    pca_transform_kernel<<<2048, 256, 0, stream>>>(
        pose, alpha_exp, alpha_shp, u_base, w_exp, w_shp, out);
}